// Round 1
// baseline (1223.028 us; speedup 1.0000x reference)
//
#include <hip/hip_runtime.h>
#include <math.h>

#define DDIM 2048
#define NCAND 65536
#define KSPLIT 32
#define BATCH 8

// ---------------------------------------------------------------------------
// Kernel A: partial sums of align_pre[j] = sum_k word[k] * W[k, j]
// Both sides (l, r) computed in one pass over W (W read once: 16 MB).
// Grid: (DDIM/256, KSPLIT), block 256. Coalesced: consecutive t -> consecutive j.
// ---------------------------------------------------------------------------
__global__ void align_partial(const float* __restrict__ wl,
                              const float* __restrict__ wr,
                              const float* __restrict__ W,
                              float* __restrict__ alignp) {
    const int j  = blockIdx.x * blockDim.x + threadIdx.x;   // 0..2047
    const int kc = blockIdx.y;                              // 0..KSPLIT-1
    const int kchunk = DDIM / KSPLIT;
    const int k0 = kc * kchunk;
    float al = 0.f, ar = 0.f;
    for (int k = k0; k < k0 + kchunk; ++k) {
        float w = W[(size_t)k * DDIM + j];
        al = fmaf(wl[k], w, al);
        ar = fmaf(wr[k], w, ar);
    }
    alignp[(size_t)(0 * KSPLIT + kc) * DDIM + j] = al;
    alignp[(size_t)(1 * KSPLIT + kc) * DDIM + j] = ar;
}

// ---------------------------------------------------------------------------
// Kernel B: align[j] = tanh(sum_kc partial + b[j]), both sides.
// ---------------------------------------------------------------------------
__global__ void align_finish(const float* __restrict__ alignp,
                             const float* __restrict__ b,
                             float* __restrict__ alignv) {
    const int j = blockIdx.x * blockDim.x + threadIdx.x;
    float sl = b[j], sr = b[j];
    for (int kc = 0; kc < KSPLIT; ++kc) {
        sl += alignp[(size_t)(0 * KSPLIT + kc) * DDIM + j];
        sr += alignp[(size_t)(1 * KSPLIT + kc) * DDIM + j];
    }
    alignv[j] = tanhf(sl);
    alignv[DDIM + j] = tanhf(sr);
}

// ---------------------------------------------------------------------------
// Kernel C: fused scores -> online softmax -> weighted accumulation.
// side 0: cand_r with align_l ; side 1: cand_l with align_r.
// Each block handles rows_per_block rows; thread t owns 8 columns
// (two contiguous float4 halves: [t*4, t*4+4) and [1024+t*4, ...)).
// Rows stashed in registers for the batch so each row is read ONCE from HBM.
// ---------------------------------------------------------------------------
__global__ __launch_bounds__(256) void score_accum(
    const float* __restrict__ cand_l, const float* __restrict__ cand_r,
    const float* __restrict__ alignv,
    float* __restrict__ accP, float* __restrict__ mP, float* __restrict__ sP,
    int B, int rows_per_block)
{
    const int side = blockIdx.y;
    const float* __restrict__ cand  = (side == 0) ? cand_r : cand_l;
    const float* __restrict__ align = alignv + (size_t)side * DDIM;

    const int t    = threadIdx.x;
    const int wave = t >> 6;
    const int lane = t & 63;
    const int c0 = t * 4;
    const int c1 = DDIM / 2 + t * 4;

    const float4 al0 = *(const float4*)(align + c0);
    const float4 al1 = *(const float4*)(align + c1);

    float4 acc0 = {0.f, 0.f, 0.f, 0.f};
    float4 acc1 = {0.f, 0.f, 0.f, 0.f};

    __shared__ float sh_part[BATCH][4];
    __shared__ float sh_w[BATCH];
    __shared__ float sh_alpha;
    __shared__ float sh_m, sh_s;
    if (t == 0) { sh_m = -INFINITY; sh_s = 0.f; }  // only thread 0 touches m/s

    const int row0 = blockIdx.x * rows_per_block;
    for (int rb = 0; rb < rows_per_block; rb += BATCH) {
        const float* rp = cand + (size_t)(row0 + rb) * DDIM;
        float4 v0[BATCH], v1[BATCH];
        float part[BATCH];
#pragma unroll
        for (int r = 0; r < BATCH; ++r) {
            v0[r] = *(const float4*)(rp + (size_t)r * DDIM + c0);
            v1[r] = *(const float4*)(rp + (size_t)r * DDIM + c1);
            part[r] = v0[r].x * al0.x + v0[r].y * al0.y + v0[r].z * al0.z + v0[r].w * al0.w
                    + v1[r].x * al1.x + v1[r].y * al1.y + v1[r].z * al1.z + v1[r].w * al1.w;
        }
        // wave-level dot reduction (64 lanes)
#pragma unroll
        for (int r = 0; r < BATCH; ++r) {
            float p = part[r];
            for (int off = 32; off > 0; off >>= 1)
                p += __shfl_down(p, off, 64);
            if (lane == 0) sh_part[r][wave] = p;
        }
        __syncthreads();
        if (t == 0) {
            float m_old = sh_m;
            float bm = m_old;
            float sc[BATCH];
#pragma unroll
            for (int r = 0; r < BATCH; ++r) {
                sc[r] = sh_part[r][0] + sh_part[r][1] + sh_part[r][2] + sh_part[r][3];
                bm = fmaxf(bm, sc[r]);
            }
            float alpha = expf(m_old - bm);   // m_old=-inf -> 0
            float ssum = 0.f;
#pragma unroll
            for (int r = 0; r < BATCH; ++r) {
                float w = expf(sc[r] - bm);
                sh_w[r] = w;
                ssum += w;
            }
            sh_s = sh_s * alpha + ssum;
            sh_m = bm;
            sh_alpha = alpha;
        }
        __syncthreads();
        const float alpha = sh_alpha;
        acc0.x *= alpha; acc0.y *= alpha; acc0.z *= alpha; acc0.w *= alpha;
        acc1.x *= alpha; acc1.y *= alpha; acc1.z *= alpha; acc1.w *= alpha;
#pragma unroll
        for (int r = 0; r < BATCH; ++r) {
            const float w = sh_w[r];
            acc0.x = fmaf(w, v0[r].x, acc0.x);
            acc0.y = fmaf(w, v0[r].y, acc0.y);
            acc0.z = fmaf(w, v0[r].z, acc0.z);
            acc0.w = fmaf(w, v0[r].w, acc0.w);
            acc1.x = fmaf(w, v1[r].x, acc1.x);
            acc1.y = fmaf(w, v1[r].y, acc1.y);
            acc1.z = fmaf(w, v1[r].z, acc1.z);
            acc1.w = fmaf(w, v1[r].w, acc1.w);
        }
        // no third barrier needed: next sh_part write happens after everyone
        // passed the second barrier; sh_w reads complete before thread0 can
        // rewrite them (it must pass the NEXT first barrier to do so).
    }
    float* acc = accP + (size_t)(side * B + blockIdx.x) * DDIM;
    *(float4*)(acc + c0) = acc0;
    *(float4*)(acc + c1) = acc1;
    if (t == 0) {
        mP[side * B + blockIdx.x] = sh_m;
        sP[side * B + blockIdx.x] = sh_s;
    }
}

// ---------------------------------------------------------------------------
// Kernel D: combine block partials: out[j] = sum_b e^{m_b-M} acc_b[j] / sum_b e^{m_b-M} s_b
// ---------------------------------------------------------------------------
__global__ void combine(const float* __restrict__ accP,
                        const float* __restrict__ mP,
                        const float* __restrict__ sP,
                        float* __restrict__ out, int B)
{
    const int side = blockIdx.y;
    const int j = blockIdx.x * blockDim.x + threadIdx.x;
    const float* m = mP + side * B;
    const float* s = sP + side * B;
    float M = -INFINITY;
    for (int b = 0; b < B; ++b) M = fmaxf(M, m[b]);
    float S = 0.f, num = 0.f;
    for (int b = 0; b < B; ++b) {
        float w = expf(m[b] - M);
        S += w * s[b];
        num = fmaf(w, accP[(size_t)(side * B + b) * DDIM + j], num);
    }
    out[(size_t)side * DDIM + j] = num / S;
}

extern "C" void kernel_launch(void* const* d_in, const int* in_sizes, int n_in,
                              void* d_out, int out_size, void* d_ws, size_t ws_size,
                              hipStream_t stream) {
    const float* wl = (const float*)d_in[0];  // embed_word_l [1,D]
    const float* wr = (const float*)d_in[1];  // embed_word_r [1,D]
    const float* cl = (const float*)d_in[2];  // embed_candidates_l [N,D]
    const float* cr = (const float*)d_in[3];  // embed_candidates_r [N,D]
    const float* W  = (const float*)d_in[4];  // W_a [D,D]
    const float* ba = (const float*)d_in[5];  // b_a [1,D]
    float* out = (float*)d_out;
    float* ws  = (float*)d_ws;

    // ws layout (floats): alignp[2][KSPLIT][D] | alignv[2][D] | mP[2][B] | sP[2][B] | accP[2][B][D]
    const size_t fixed_f = (size_t)2 * KSPLIT * DDIM + (size_t)2 * DDIM;
    int B = 512;  // blocks per side; power of two so it divides NCAND
    while (B > 8) {
        size_t need = (fixed_f + (size_t)4 * B + (size_t)2 * B * DDIM) * sizeof(float);
        if (need <= ws_size) break;
        B >>= 1;
    }
    const int rpb = NCAND / B;  // multiple of BATCH for all B >= 8

    float* alignp = ws;
    float* alignv = alignp + (size_t)2 * KSPLIT * DDIM;
    float* mP     = alignv + (size_t)2 * DDIM;
    float* sP     = mP + (size_t)2 * B;
    float* accP   = sP + (size_t)2 * B;

    align_partial<<<dim3(DDIM / 256, KSPLIT), 256, 0, stream>>>(wl, wr, W, alignp);
    align_finish<<<dim3(DDIM / 256), 256, 0, stream>>>(alignp, ba, alignv);
    score_accum<<<dim3(B, 2), 256, 0, stream>>>(cl, cr, alignv, accP, mP, sP, B, rpb);
    combine<<<dim3(DDIM / 256, 2), 256, 0, stream>>>(accP, mP, sP, out, B);
}

// Round 2
// 1163.374 us; speedup vs baseline: 1.0513x; 1.0513x over previous
//
#include <hip/hip_runtime.h>
#include <math.h>

#define DDIM 2048
#define NCAND 65536
#define KSPLIT 32

// ---------------------------------------------------------------------------
// Kernel A: partial sums of align_pre[j] = sum_k word[k] * W[k, j]
// Both sides (l, r) computed in one pass over W (W read once: 16 MB).
// ---------------------------------------------------------------------------
__global__ void align_partial(const float* __restrict__ wl,
                              const float* __restrict__ wr,
                              const float* __restrict__ W,
                              float* __restrict__ alignp) {
    const int j  = blockIdx.x * blockDim.x + threadIdx.x;   // 0..2047
    const int kc = blockIdx.y;                              // 0..KSPLIT-1
    const int kchunk = DDIM / KSPLIT;
    const int k0 = kc * kchunk;
    float al = 0.f, ar = 0.f;
    for (int k = k0; k < k0 + kchunk; ++k) {
        float w = W[(size_t)k * DDIM + j];
        al = fmaf(wl[k], w, al);
        ar = fmaf(wr[k], w, ar);
    }
    alignp[(size_t)(0 * KSPLIT + kc) * DDIM + j] = al;
    alignp[(size_t)(1 * KSPLIT + kc) * DDIM + j] = ar;
}

// ---------------------------------------------------------------------------
// Kernel B: align[j] = tanh(sum_kc partial + b[j]), both sides.
// ---------------------------------------------------------------------------
__global__ void align_finish(const float* __restrict__ alignp,
                             const float* __restrict__ b,
                             float* __restrict__ alignv) {
    const int j = blockIdx.x * blockDim.x + threadIdx.x;
    float sl = b[j], sr = b[j];
    for (int kc = 0; kc < KSPLIT; ++kc) {
        sl += alignp[(size_t)(0 * KSPLIT + kc) * DDIM + j];
        sr += alignp[(size_t)(1 * KSPLIT + kc) * DDIM + j];
    }
    alignv[j] = tanhf(sl);
    alignv[DDIM + j] = tanhf(sr);
}

// ---------------------------------------------------------------------------
// Kernel C: fused scores -> online softmax -> weighted accumulation.
// PER-WAVE design: each wave owns rows_per_wave rows across ALL 2048 cols
// (lane l holds 8 float4 chunks: col = c*256 + l*4, c=0..7 -> each load
// instruction covers 1 KB contiguous). Butterfly shfl_xor dot-reduce, lane-0
// broadcast for bit-identical state, branch-skipped rescale. NO barriers, NO
// LDS in the hot loop. One end-of-kernel LDS merge of the 4 wave partials.
// ---------------------------------------------------------------------------
__global__ __launch_bounds__(256, 4) void score_accum(
    const float* __restrict__ cand_l, const float* __restrict__ cand_r,
    const float* __restrict__ alignv,
    float* __restrict__ accP, float* __restrict__ mP, float* __restrict__ sP,
    int B, int rows_per_wave)
{
    const int side = blockIdx.y;
    const float* __restrict__ cand  = (side == 0) ? cand_r : cand_l;
    const float* __restrict__ align = alignv + (size_t)side * DDIM;

    const int t = threadIdx.x;
    const int w = t >> 6;
    const int l = t & 63;
    const int cbase = l * 4;

    float4 al[8], acc[8];
#pragma unroll
    for (int c = 0; c < 8; ++c) {
        al[c]  = *(const float4*)(align + c * 256 + cbase);
        acc[c] = make_float4(0.f, 0.f, 0.f, 0.f);
    }
    float m = -INFINITY, s = 0.f;

    const int row0 = (blockIdx.x * 4 + w) * rows_per_wave;
    for (int r = 0; r < rows_per_wave; ++r) {
        const float* rp = cand + (size_t)(row0 + r) * DDIM;
        float4 v[8];
#pragma unroll
        for (int c = 0; c < 8; ++c)
            v[c] = *(const float4*)(rp + c * 256 + cbase);
        float p = 0.f;
#pragma unroll
        for (int c = 0; c < 8; ++c) {
            p = fmaf(v[c].x, al[c].x, p);
            p = fmaf(v[c].y, al[c].y, p);
            p = fmaf(v[c].z, al[c].z, p);
            p = fmaf(v[c].w, al[c].w, p);
        }
#pragma unroll
        for (int off = 32; off > 0; off >>= 1)
            p += __shfl_xor(p, off, 64);
        p = __shfl(p, 0, 64);          // bit-identical score on all lanes

        if (p > m) {                   // wave-uniform, rare (~ln N times)
            float alpha = expf(m - p); // m=-inf on first hit -> alpha=0
            m = p;
            s = fmaf(s, alpha, 1.f);   // w = exp(p - m_new) = 1
#pragma unroll
            for (int c = 0; c < 8; ++c) {
                acc[c].x = fmaf(acc[c].x, alpha, v[c].x);
                acc[c].y = fmaf(acc[c].y, alpha, v[c].y);
                acc[c].z = fmaf(acc[c].z, alpha, v[c].z);
                acc[c].w = fmaf(acc[c].w, alpha, v[c].w);
            }
        } else {
            float wgt = expf(p - m);
            s += wgt;
#pragma unroll
            for (int c = 0; c < 8; ++c) {
                acc[c].x = fmaf(wgt, v[c].x, acc[c].x);
                acc[c].y = fmaf(wgt, v[c].y, acc[c].y);
                acc[c].z = fmaf(wgt, v[c].z, acc[c].z);
                acc[c].w = fmaf(wgt, v[c].w, acc[c].w);
            }
        }
    }

    // ---- merge 4 wave-partials -> 1 block-partial via LDS (single barrier)
    __shared__ float sh_acc[4][DDIM];
    __shared__ float sh_m[4], sh_s[4];
#pragma unroll
    for (int c = 0; c < 8; ++c)
        *(float4*)(&sh_acc[w][c * 256 + cbase]) = acc[c];
    if (l == 0) { sh_m[w] = m; sh_s[w] = s; }
    __syncthreads();

    const float mB = fmaxf(fmaxf(sh_m[0], sh_m[1]), fmaxf(sh_m[2], sh_m[3]));
    const float e0 = expf(sh_m[0] - mB);
    const float e1 = expf(sh_m[1] - mB);
    const float e2 = expf(sh_m[2] - mB);
    const float e3 = expf(sh_m[3] - mB);
    const float sB = e0 * sh_s[0] + e1 * sh_s[1] + e2 * sh_s[2] + e3 * sh_s[3];

    float* accB = accP + (size_t)(side * B + blockIdx.x) * DDIM;
#pragma unroll
    for (int half = 0; half < 2; ++half) {
        const int col = half * 1024 + t * 4;
        const float4 a0 = *(const float4*)&sh_acc[0][col];
        const float4 a1 = *(const float4*)&sh_acc[1][col];
        const float4 a2 = *(const float4*)&sh_acc[2][col];
        const float4 a3 = *(const float4*)&sh_acc[3][col];
        float4 o;
        o.x = e0 * a0.x + e1 * a1.x + e2 * a2.x + e3 * a3.x;
        o.y = e0 * a0.y + e1 * a1.y + e2 * a2.y + e3 * a3.y;
        o.z = e0 * a0.z + e1 * a1.z + e2 * a2.z + e3 * a3.z;
        o.w = e0 * a0.w + e1 * a1.w + e2 * a2.w + e3 * a3.w;
        *(float4*)(accB + col) = o;
    }
    if (t == 0) {
        mP[side * B + blockIdx.x] = mB;
        sP[side * B + blockIdx.x] = sB;
    }
}

// ---------------------------------------------------------------------------
// Kernel D: combine block partials:
// out[j] = sum_b e^{m_b-M} acc_b[j] / sum_b e^{m_b-M} s_b
// ---------------------------------------------------------------------------
__global__ void combine(const float* __restrict__ accP,
                        const float* __restrict__ mP,
                        const float* __restrict__ sP,
                        float* __restrict__ out, int B)
{
    const int side = blockIdx.y;
    const int j = blockIdx.x * blockDim.x + threadIdx.x;
    const float* m = mP + side * B;
    const float* s = sP + side * B;
    float M = -INFINITY;
    for (int b = 0; b < B; ++b) M = fmaxf(M, m[b]);
    float S = 0.f, num = 0.f;
    for (int b = 0; b < B; ++b) {
        float w = expf(m[b] - M);
        S += w * s[b];
        num = fmaf(w, accP[(size_t)(side * B + b) * DDIM + j], num);
    }
    out[(size_t)side * DDIM + j] = num / S;
}

extern "C" void kernel_launch(void* const* d_in, const int* in_sizes, int n_in,
                              void* d_out, int out_size, void* d_ws, size_t ws_size,
                              hipStream_t stream) {
    const float* wl = (const float*)d_in[0];  // embed_word_l [1,D]
    const float* wr = (const float*)d_in[1];  // embed_word_r [1,D]
    const float* cl = (const float*)d_in[2];  // embed_candidates_l [N,D]
    const float* cr = (const float*)d_in[3];  // embed_candidates_r [N,D]
    const float* W  = (const float*)d_in[4];  // W_a [D,D]
    const float* ba = (const float*)d_in[5];  // b_a [1,D]
    float* out = (float*)d_out;
    float* ws  = (float*)d_ws;

    // ws layout (floats): alignp[2][KSPLIT][D] | alignv[2][D] | mP[2][B] | sP[2][B] | accP[2][B][D]
    const size_t fixed_f = (size_t)2 * KSPLIT * DDIM + (size_t)2 * DDIM;
    int B = 512;  // blocks per side; power of two so it divides NCAND
    while (B > 8) {
        size_t need = (fixed_f + (size_t)4 * B + (size_t)2 * B * DDIM) * sizeof(float);
        if (need <= ws_size) break;
        B >>= 1;
    }
    const int rpw = NCAND / (B * 4);  // rows per wave (4 waves per block)

    float* alignp = ws;
    float* alignv = alignp + (size_t)2 * KSPLIT * DDIM;
    float* mP     = alignv + (size_t)2 * DDIM;
    float* sP     = mP + (size_t)2 * B;
    float* accP   = sP + (size_t)2 * B;

    align_partial<<<dim3(DDIM / 256, KSPLIT), 256, 0, stream>>>(wl, wr, W, alignp);
    align_finish<<<dim3(DDIM / 256), 256, 0, stream>>>(alignp, ba, alignv);
    score_accum<<<dim3(B, 2), 256, 0, stream>>>(cl, cr, alignv, accP, mP, sP, B, rpw);
    combine<<<dim3(DDIM / 256, 2), 256, 0, stream>>>(accP, mP, sP, out, B);
}